// Round 1
// baseline (190.759 us; speedup 1.0000x reference)
//
#include <hip/hip_runtime.h>
#include <hip/hip_bf16.h>
#include <hip/hip_fp16.h>

// SkipGramNS: out[i] = dot(cxt_weight[ctx[i]], tgt_weight[tgt[i]]), D=128.
// R6: restructure gather to 1 lane/pair. The 8-lane/pair scheme paid ~50 VALU
// ops/pair in shfl-reduce + 8x-redundant idx/scale broadcasts and a lane-0-only
// store. Now each lane owns a full pair: 8+8 int4 loads (both 128-B rows),
// 32 sdot4, no cross-lane ops, coalesced idx loads and out stores. Per-wave
// outstanding bytes double (8KB -> 16KB) for L3-latency hiding.
// Convert pass unchanged (streams 129 MB, already at HBM floor ~20 us).

#define D 128

// 4x int8 dot-accumulate. Prefer the HW sdot4 if available.
#if defined(__has_builtin)
#if __has_builtin(__builtin_amdgcn_sdot4)
#define HAVE_SDOT4 1
#endif
#endif

__device__ __forceinline__ int dot4_i8(int a, int b, int c) {
#ifdef HAVE_SDOT4
    return __builtin_amdgcn_sdot4(a, b, c, false);
#else
    c += ((a << 24) >> 24) * ((b << 24) >> 24);
    c += ((a << 16) >> 24) * ((b << 16) >> 24);
    c += ((a <<  8) >> 24) * ((b <<  8) >> 24);
    c += ( a        >> 24) * ( b        >> 24);
    return c;
#endif
}

// ---- Pass 1: fp32 rows -> int8 rows + per-row scale. 16 lanes/row, 8 elems/lane ----
__global__ __launch_bounds__(256) void convert_int8_kernel(
    const float* __restrict__ cxt_w, const float* __restrict__ tgt_w,
    signed char* __restrict__ cxt_q, signed char* __restrict__ tgt_q,
    float* __restrict__ cxt_s, float* __restrict__ tgt_s, int V)
{
    const int row  = blockIdx.x * 16 + (threadIdx.x >> 4);
    const int lane = threadIdx.x & 15;
    if (row >= 2 * V) return;

    const float* src; signed char* dq; float* ds; int r;
    if (row < V) { src = cxt_w; dq = cxt_q; ds = cxt_s; r = row; }
    else         { src = tgt_w; dq = tgt_q; ds = tgt_s; r = row - V; }

    const float4 a = *reinterpret_cast<const float4*>(src + (size_t)r * D + lane * 8);
    const float4 b = *reinterpret_cast<const float4*>(src + (size_t)r * D + lane * 8 + 4);

    float m = fabsf(a.x);
    m = fmaxf(m, fabsf(a.y)); m = fmaxf(m, fabsf(a.z)); m = fmaxf(m, fabsf(a.w));
    m = fmaxf(m, fabsf(b.x)); m = fmaxf(m, fabsf(b.y));
    m = fmaxf(m, fabsf(b.z)); m = fmaxf(m, fabsf(b.w));
    // row max across the 16-lane group (masks stay inside the group)
    m = fmaxf(m, __shfl_xor(m, 8));
    m = fmaxf(m, __shfl_xor(m, 4));
    m = fmaxf(m, __shfl_xor(m, 2));
    m = fmaxf(m, __shfl_xor(m, 1));

    const float inv = (m > 0.f) ? 127.f / m : 0.f;

    const float v[8] = {a.x, a.y, a.z, a.w, b.x, b.y, b.z, b.w};
    int q[8];
    #pragma unroll
    for (int k = 0; k < 8; ++k) {
        int t = (int)__builtin_rintf(v[k] * inv);
        t = t > 127 ? 127 : (t < -127 ? -127 : t);
        q[k] = t & 255;
    }
    int2 packed;
    packed.x = q[0] | (q[1] << 8) | (q[2] << 16) | (q[3] << 24);
    packed.y = q[4] | (q[5] << 8) | (q[6] << 16) | (q[7] << 24);
    *reinterpret_cast<int2*>(dq + (size_t)r * D + lane * 8) = packed;

    if (lane == 0) ds[r] = m * (1.f / 127.f);
}

// ---- Pass 2: int8 gather + exact int dot. 1 lane per pair: 8+8 int4 loads
//      cover both 128-B rows; no cross-lane reduce; coalesced out store. ----
__global__ __launch_bounds__(256) void gather_dot_q1_kernel(
    const int* __restrict__ ctx_idx, const int* __restrict__ tgt_idx,
    const signed char* __restrict__ cxt_q, const signed char* __restrict__ tgt_q,
    const float* __restrict__ cxt_s, const float* __restrict__ tgt_s,
    float* __restrict__ out, int n)
{
    const int p = blockIdx.x * blockDim.x + threadIdx.x;
    if (p >= n) return;

    const int ci = ctx_idx[p];
    const int ti = tgt_idx[p];
    const int4* __restrict__ cr = reinterpret_cast<const int4*>(cxt_q + (size_t)ci * D);
    const int4* __restrict__ tr = reinterpret_cast<const int4*>(tgt_q + (size_t)ti * D);

    // Issue all 16 row loads up front (16 KB/wave outstanding) before any use.
    int4 qc[8], qt[8];
    #pragma unroll
    for (int k = 0; k < 8; ++k) qc[k] = cr[k];
    #pragma unroll
    for (int k = 0; k < 8; ++k) qt[k] = tr[k];
    const float sc = cxt_s[ci];
    const float st = tgt_s[ti];

    int s = 0;
    #pragma unroll
    for (int k = 0; k < 8; ++k) {
        s = dot4_i8(qc[k].x, qt[k].x, s);
        s = dot4_i8(qc[k].y, qt[k].y, s);
        s = dot4_i8(qc[k].z, qt[k].z, s);
        s = dot4_i8(qc[k].w, qt[k].w, s);
    }
    __builtin_nontemporal_store((float)s * sc * st, out + p);
}

// ---- Fallback (ws too small): fp32 direct ----
__global__ __launch_bounds__(256) void gather_dot_f32_kernel(
    const int* __restrict__ ctx_idx, const int* __restrict__ tgt_idx,
    const float* __restrict__ cxt_w, const float* __restrict__ tgt_w,
    float* __restrict__ out, int n)
{
    const int lane = threadIdx.x & 31;
    const long long g = ((long long)blockIdx.x * blockDim.x + threadIdx.x) >> 5;
    const int pair = (int)g;
    if (pair >= n) return;
    const float4 c = reinterpret_cast<const float4*>(cxt_w + (size_t)ctx_idx[pair] * D)[lane];
    const float4 t = reinterpret_cast<const float4*>(tgt_w + (size_t)tgt_idx[pair] * D)[lane];
    float s = c.x * t.x;
    s = fmaf(c.y, t.y, s);
    s = fmaf(c.z, t.z, s);
    s = fmaf(c.w, t.w, s);
    s += __shfl_xor(s, 16);
    s += __shfl_xor(s, 8);
    s += __shfl_xor(s, 4);
    s += __shfl_xor(s, 2);
    s += __shfl_xor(s, 1);
    if (lane == 0) out[pair] = s;
}

extern "C" void kernel_launch(void* const* d_in, const int* in_sizes, int n_in,
                              void* d_out, int out_size, void* d_ws, size_t ws_size,
                              hipStream_t stream) {
    const int*   ctx_idx = (const int*)d_in[0];
    const int*   tgt_idx = (const int*)d_in[1];
    const float* cxt_w   = (const float*)d_in[2];
    const float* tgt_w   = (const float*)d_in[3];
    float*       out     = (float*)d_out;

    const int n = in_sizes[0];        // N pairs
    const int elems = in_sizes[2];    // V*D per table
    const int V = elems / D;

    const size_t qtab = (size_t)V * D;                    // bytes per int8 table
    const size_t need = 2 * qtab + 2 * (size_t)V * sizeof(float) + 64;

    if (ws_size >= need) {
        char* p = (char*)d_ws;
        signed char* cxt_q = (signed char*)p;  p += qtab;
        signed char* tgt_q = (signed char*)p;  p += qtab;
        float* cxt_s = (float*)p;              p += (size_t)V * sizeof(float);
        float* tgt_s = (float*)p;

        // Pass 1: quantize both tables (16 rows per block).
        const int conv_grid = (2 * V + 15) / 16;
        convert_int8_kernel<<<conv_grid, 256, 0, stream>>>(
            cxt_w, tgt_w, cxt_q, tgt_q, cxt_s, tgt_s, V);

        // Pass 2: gather + int8 dot, 1 lane/pair, 256 pairs/block.
        const int grid = (n + 255) / 256;
        gather_dot_q1_kernel<<<grid, 256, 0, stream>>>(
            ctx_idx, tgt_idx, cxt_q, tgt_q, cxt_s, tgt_s, out, n);
    } else {
        gather_dot_f32_kernel<<<(n + 7) / 8, 256, 0, stream>>>(
            ctx_idx, tgt_idx, cxt_w, tgt_w, out, n);
    }
}

// Round 3
// 168.034 us; speedup vs baseline: 1.1352x; 1.1352x over previous
//
#include <hip/hip_runtime.h>
#include <hip/hip_bf16.h>
#include <hip/hip_fp16.h>

// SkipGramNS: out[i] = dot(cxt_weight[ctx[i]], tgt_weight[tgt[i]]), D=128.
// R8 = R7 with the nontemporal builtin type error fixed (ext_vector_type
// instead of HIP_vector_type for __builtin_nontemporal_*).
// R7 rationale: revert R6's 1-lane/pair (address-divergence bound: 64 distinct
// cache lines per wave load instr, VALUBusy 1.8%, 64 us). Back to 8 lanes/pair
// (8x16B contiguous per row = coalesced 128-B segments), with 8 pairs/group
// (16 KB/wave outstanding, all loads issued before first sdot) and nontemporal
// idx loads / out stores (streaming, keep caches for rows).

#define D 128

typedef int   vint4   __attribute__((ext_vector_type(4)));
typedef float vfloat4 __attribute__((ext_vector_type(4)));

#if defined(__has_builtin)
#if __has_builtin(__builtin_amdgcn_sdot4)
#define HAVE_SDOT4 1
#endif
#endif

__device__ __forceinline__ int dot4_i8(int a, int b, int c) {
#ifdef HAVE_SDOT4
    return __builtin_amdgcn_sdot4(a, b, c, false);
#else
    c += ((a << 24) >> 24) * ((b << 24) >> 24);
    c += ((a << 16) >> 24) * ((b << 16) >> 24);
    c += ((a <<  8) >> 24) * ((b <<  8) >> 24);
    c += ( a        >> 24) * ( b        >> 24);
    return c;
#endif
}

// ---- Pass 1: fp32 rows -> int8 rows + per-row scale. 16 lanes/row, 8 elems/lane ----
__global__ __launch_bounds__(256) void convert_int8_kernel(
    const float* __restrict__ cxt_w, const float* __restrict__ tgt_w,
    signed char* __restrict__ cxt_q, signed char* __restrict__ tgt_q,
    float* __restrict__ cxt_s, float* __restrict__ tgt_s, int V)
{
    const int row  = blockIdx.x * 16 + (threadIdx.x >> 4);
    const int lane = threadIdx.x & 15;
    if (row >= 2 * V) return;

    const float* src; signed char* dq; float* ds; int r;
    if (row < V) { src = cxt_w; dq = cxt_q; ds = cxt_s; r = row; }
    else         { src = tgt_w; dq = tgt_q; ds = tgt_s; r = row - V; }

    const float4 a = *reinterpret_cast<const float4*>(src + (size_t)r * D + lane * 8);
    const float4 b = *reinterpret_cast<const float4*>(src + (size_t)r * D + lane * 8 + 4);

    float m = fabsf(a.x);
    m = fmaxf(m, fabsf(a.y)); m = fmaxf(m, fabsf(a.z)); m = fmaxf(m, fabsf(a.w));
    m = fmaxf(m, fabsf(b.x)); m = fmaxf(m, fabsf(b.y));
    m = fmaxf(m, fabsf(b.z)); m = fmaxf(m, fabsf(b.w));
    m = fmaxf(m, __shfl_xor(m, 8));
    m = fmaxf(m, __shfl_xor(m, 4));
    m = fmaxf(m, __shfl_xor(m, 2));
    m = fmaxf(m, __shfl_xor(m, 1));

    const float inv = (m > 0.f) ? 127.f / m : 0.f;

    const float v[8] = {a.x, a.y, a.z, a.w, b.x, b.y, b.z, b.w};
    int q[8];
    #pragma unroll
    for (int k = 0; k < 8; ++k) {
        int t = (int)__builtin_rintf(v[k] * inv);
        t = t > 127 ? 127 : (t < -127 ? -127 : t);
        q[k] = t & 255;
    }
    int2 packed;
    packed.x = q[0] | (q[1] << 8) | (q[2] << 16) | (q[3] << 24);
    packed.y = q[4] | (q[5] << 8) | (q[6] << 16) | (q[7] << 24);
    *reinterpret_cast<int2*>(dq + (size_t)r * D + lane * 8) = packed;

    if (lane == 0) ds[r] = m * (1.f / 127.f);
}

// ---- Pass 2: int8 gather + exact int dot. 8 lanes/pair (8 x 16B = 128B row),
//      8 pairs per 8-lane group; all 16 row loads issued before first dot. ----
__global__ __launch_bounds__(256) void gather_dot_q_kernel(
    const int* __restrict__ ctx_idx, const int* __restrict__ tgt_idx,
    const signed char* __restrict__ cxt_q, const signed char* __restrict__ tgt_q,
    const float* __restrict__ cxt_s, const float* __restrict__ tgt_s,
    float* __restrict__ out, int n)
{
    const int lane = threadIdx.x & 7;
    const long long g = ((long long)blockIdx.x * blockDim.x + threadIdx.x) >> 3;
    const int p0 = (int)(g << 3);   // 8 pairs per group
    if (p0 >= n) return;

    if (p0 + 8 <= n) {
        const vint4 ciA = __builtin_nontemporal_load(reinterpret_cast<const vint4*>(ctx_idx + p0));
        const vint4 ciB = __builtin_nontemporal_load(reinterpret_cast<const vint4*>(ctx_idx + p0 + 4));
        const vint4 tiA = __builtin_nontemporal_load(reinterpret_cast<const vint4*>(tgt_idx + p0));
        const vint4 tiB = __builtin_nontemporal_load(reinterpret_cast<const vint4*>(tgt_idx + p0 + 4));
        const int ci[8] = {ciA.x, ciA.y, ciA.z, ciA.w, ciB.x, ciB.y, ciB.z, ciB.w};
        const int ti[8] = {tiA.x, tiA.y, tiA.z, tiA.w, tiB.x, tiB.y, tiB.z, tiB.w};

        // Issue all 16 coalesced row loads (16 KB/wave in flight) up front.
        int4 qc[8], qt[8];
        #pragma unroll
        for (int u = 0; u < 8; ++u)
            qc[u] = *reinterpret_cast<const int4*>(cxt_q + (size_t)ci[u] * D + lane * 16);
        #pragma unroll
        for (int u = 0; u < 8; ++u)
            qt[u] = *reinterpret_cast<const int4*>(tgt_q + (size_t)ti[u] * D + lane * 16);

        float sc[8], st[8];
        #pragma unroll
        for (int u = 0; u < 8; ++u) { sc[u] = cxt_s[ci[u]]; st[u] = tgt_s[ti[u]]; }

        int acc[8];
        #pragma unroll
        for (int u = 0; u < 8; ++u) {
            int s = dot4_i8(qc[u].x, qt[u].x, 0);
            s = dot4_i8(qc[u].y, qt[u].y, s);
            s = dot4_i8(qc[u].z, qt[u].z, s);
            s = dot4_i8(qc[u].w, qt[u].w, s);
            acc[u] = s;
        }
        #pragma unroll
        for (int u = 0; u < 8; ++u) {
            acc[u] += __shfl_xor(acc[u], 4);
            acc[u] += __shfl_xor(acc[u], 2);
            acc[u] += __shfl_xor(acc[u], 1);
        }
        if (lane == 0) {
            vfloat4 o0, o1;
            o0.x = (float)acc[0] * sc[0] * st[0];
            o0.y = (float)acc[1] * sc[1] * st[1];
            o0.z = (float)acc[2] * sc[2] * st[2];
            o0.w = (float)acc[3] * sc[3] * st[3];
            o1.x = (float)acc[4] * sc[4] * st[4];
            o1.y = (float)acc[5] * sc[5] * st[5];
            o1.z = (float)acc[6] * sc[6] * st[6];
            o1.w = (float)acc[7] * sc[7] * st[7];
            __builtin_nontemporal_store(o0, reinterpret_cast<vfloat4*>(out + p0));
            __builtin_nontemporal_store(o1, reinterpret_cast<vfloat4*>(out + p0 + 4));
        }
    } else {
        for (int u = 0; u < 8 && p0 + u < n; ++u) {
            const int pi = p0 + u;
            const int ci = ctx_idx[pi];
            const int ti = tgt_idx[pi];
            const int4 qc = *reinterpret_cast<const int4*>(cxt_q + (size_t)ci * D + lane * 16);
            const int4 qt = *reinterpret_cast<const int4*>(tgt_q + (size_t)ti * D + lane * 16);
            int s = dot4_i8(qc.x, qt.x, 0);
            s = dot4_i8(qc.y, qt.y, s);
            s = dot4_i8(qc.z, qt.z, s);
            s = dot4_i8(qc.w, qt.w, s);
            s += __shfl_xor(s, 4);
            s += __shfl_xor(s, 2);
            s += __shfl_xor(s, 1);
            if (lane == 0) out[pi] = (float)s * cxt_s[ci] * tgt_s[ti];
        }
    }
}

// ---- Fallback (ws too small): fp32 direct ----
__global__ __launch_bounds__(256) void gather_dot_f32_kernel(
    const int* __restrict__ ctx_idx, const int* __restrict__ tgt_idx,
    const float* __restrict__ cxt_w, const float* __restrict__ tgt_w,
    float* __restrict__ out, int n)
{
    const int lane = threadIdx.x & 31;
    const long long g = ((long long)blockIdx.x * blockDim.x + threadIdx.x) >> 5;
    const int pair = (int)g;
    if (pair >= n) return;
    const float4 c = reinterpret_cast<const float4*>(cxt_w + (size_t)ctx_idx[pair] * D)[lane];
    const float4 t = reinterpret_cast<const float4*>(tgt_w + (size_t)tgt_idx[pair] * D)[lane];
    float s = c.x * t.x;
    s = fmaf(c.y, t.y, s);
    s = fmaf(c.z, t.z, s);
    s = fmaf(c.w, t.w, s);
    s += __shfl_xor(s, 16);
    s += __shfl_xor(s, 8);
    s += __shfl_xor(s, 4);
    s += __shfl_xor(s, 2);
    s += __shfl_xor(s, 1);
    if (lane == 0) out[pair] = s;
}

extern "C" void kernel_launch(void* const* d_in, const int* in_sizes, int n_in,
                              void* d_out, int out_size, void* d_ws, size_t ws_size,
                              hipStream_t stream) {
    const int*   ctx_idx = (const int*)d_in[0];
    const int*   tgt_idx = (const int*)d_in[1];
    const float* cxt_w   = (const float*)d_in[2];
    const float* tgt_w   = (const float*)d_in[3];
    float*       out     = (float*)d_out;

    const int n = in_sizes[0];        // N pairs
    const int elems = in_sizes[2];    // V*D per table
    const int V = elems / D;

    const size_t qtab = (size_t)V * D;                    // bytes per int8 table
    const size_t need = 2 * qtab + 2 * (size_t)V * sizeof(float) + 64;

    if (ws_size >= need) {
        char* p = (char*)d_ws;
        signed char* cxt_q = (signed char*)p;  p += qtab;
        signed char* tgt_q = (signed char*)p;  p += qtab;
        float* cxt_s = (float*)p;              p += (size_t)V * sizeof(float);
        float* tgt_s = (float*)p;

        // Pass 1: quantize both tables (16 rows per block).
        const int conv_grid = (2 * V + 15) / 16;
        convert_int8_kernel<<<conv_grid, 256, 0, stream>>>(
            cxt_w, tgt_w, cxt_q, tgt_q, cxt_s, tgt_s, V);

        // Pass 2: gather + int8 dot. 8 lanes/pair, 8 pairs/group -> 256 pairs/block.
        const int pairs_per_block = (256 / 8) * 8;
        const int grid = (n + pairs_per_block - 1) / pairs_per_block;
        gather_dot_q_kernel<<<grid, 256, 0, stream>>>(
            ctx_idx, tgt_idx, cxt_q, tgt_q, cxt_s, tgt_s, out, n);
    } else {
        gather_dot_f32_kernel<<<(n + 7) / 8, 256, 0, stream>>>(
            ctx_idx, tgt_idx, cxt_w, tgt_w, out, n);
    }
}

// Round 4
// 163.861 us; speedup vs baseline: 1.1641x; 1.0255x over previous
//
#include <hip/hip_runtime.h>
#include <hip/hip_bf16.h>
#include <hip/hip_fp16.h>

// SkipGramNS: out[i] = dot(cxt_weight[ctx[i]], tgt_weight[tgt[i]]), D=128.
// R9: revert to R5's 4-pairs/group gather (best measured, 164.9 us). R8's
// 8-pairs/group doubled per-wave VGPR payload -> occupancy drop; for this
// latency-bound random gather TLP > per-wave MLP (R6: VALUBusy 1.8%, so
// issue-rate/VALU never mattered). Keep the one free R8 improvement:
// nontemporal out stores (streaming; preserves L2 for table rows).
// Structure: 8 lanes/pair (8x16B = coalesced 128-B row segments), 4 pairs
// per 8-lane group, shfl-xor reduce, lane-0 float4 NT store.

#define D 128

typedef float vfloat4 __attribute__((ext_vector_type(4)));

#if defined(__has_builtin)
#if __has_builtin(__builtin_amdgcn_sdot4)
#define HAVE_SDOT4 1
#endif
#endif

__device__ __forceinline__ int dot4_i8(int a, int b, int c) {
#ifdef HAVE_SDOT4
    return __builtin_amdgcn_sdot4(a, b, c, false);
#else
    c += ((a << 24) >> 24) * ((b << 24) >> 24);
    c += ((a << 16) >> 24) * ((b << 16) >> 24);
    c += ((a <<  8) >> 24) * ((b <<  8) >> 24);
    c += ( a        >> 24) * ( b        >> 24);
    return c;
#endif
}

// ---- Pass 1: fp32 rows -> int8 rows + per-row scale. 16 lanes/row, 8 elems/lane ----
__global__ __launch_bounds__(256) void convert_int8_kernel(
    const float* __restrict__ cxt_w, const float* __restrict__ tgt_w,
    signed char* __restrict__ cxt_q, signed char* __restrict__ tgt_q,
    float* __restrict__ cxt_s, float* __restrict__ tgt_s, int V)
{
    const int row  = blockIdx.x * 16 + (threadIdx.x >> 4);
    const int lane = threadIdx.x & 15;
    if (row >= 2 * V) return;

    const float* src; signed char* dq; float* ds; int r;
    if (row < V) { src = cxt_w; dq = cxt_q; ds = cxt_s; r = row; }
    else         { src = tgt_w; dq = tgt_q; ds = tgt_s; r = row - V; }

    const float4 a = *reinterpret_cast<const float4*>(src + (size_t)r * D + lane * 8);
    const float4 b = *reinterpret_cast<const float4*>(src + (size_t)r * D + lane * 8 + 4);

    float m = fabsf(a.x);
    m = fmaxf(m, fabsf(a.y)); m = fmaxf(m, fabsf(a.z)); m = fmaxf(m, fabsf(a.w));
    m = fmaxf(m, fabsf(b.x)); m = fmaxf(m, fabsf(b.y));
    m = fmaxf(m, fabsf(b.z)); m = fmaxf(m, fabsf(b.w));
    // row max across the 16-lane group (masks stay inside the group)
    m = fmaxf(m, __shfl_xor(m, 8));
    m = fmaxf(m, __shfl_xor(m, 4));
    m = fmaxf(m, __shfl_xor(m, 2));
    m = fmaxf(m, __shfl_xor(m, 1));

    const float inv = (m > 0.f) ? 127.f / m : 0.f;

    const float v[8] = {a.x, a.y, a.z, a.w, b.x, b.y, b.z, b.w};
    int q[8];
    #pragma unroll
    for (int k = 0; k < 8; ++k) {
        int t = (int)__builtin_rintf(v[k] * inv);
        t = t > 127 ? 127 : (t < -127 ? -127 : t);
        q[k] = t & 255;
    }
    int2 packed;
    packed.x = q[0] | (q[1] << 8) | (q[2] << 16) | (q[3] << 24);
    packed.y = q[4] | (q[5] << 8) | (q[6] << 16) | (q[7] << 24);
    *reinterpret_cast<int2*>(dq + (size_t)r * D + lane * 8) = packed;

    if (lane == 0) ds[r] = m * (1.f / 127.f);
}

// ---- Pass 2: int8 gather + exact int dot. 8 lanes/pair (8 x 16B = 128B row),
//      4 pairs per 8-lane group ----
__global__ __launch_bounds__(256) void gather_dot_q_kernel(
    const int* __restrict__ ctx_idx, const int* __restrict__ tgt_idx,
    const signed char* __restrict__ cxt_q, const signed char* __restrict__ tgt_q,
    const float* __restrict__ cxt_s, const float* __restrict__ tgt_s,
    float* __restrict__ out, int n)
{
    const int lane = threadIdx.x & 7;
    const long long g = ((long long)blockIdx.x * blockDim.x + threadIdx.x) >> 3;
    const int p0 = (int)(g << 2);
    if (p0 >= n) return;

    if (p0 + 4 <= n) {
        const int4 ci4 = *reinterpret_cast<const int4*>(ctx_idx + p0);
        const int4 ti4 = *reinterpret_cast<const int4*>(tgt_idx + p0);
        const int ci[4] = {ci4.x, ci4.y, ci4.z, ci4.w};
        const int ti[4] = {ti4.x, ti4.y, ti4.z, ti4.w};

        int4 qc[4], qt[4];
        #pragma unroll
        for (int u = 0; u < 4; ++u) {
            qc[u] = *reinterpret_cast<const int4*>(cxt_q + (size_t)ci[u] * D + lane * 16);
            qt[u] = *reinterpret_cast<const int4*>(tgt_q + (size_t)ti[u] * D + lane * 16);
        }
        float sc[4], st[4];
        #pragma unroll
        for (int u = 0; u < 4; ++u) { sc[u] = cxt_s[ci[u]]; st[u] = tgt_s[ti[u]]; }

        int acc[4];
        #pragma unroll
        for (int u = 0; u < 4; ++u) {
            int s = dot4_i8(qc[u].x, qt[u].x, 0);
            s = dot4_i8(qc[u].y, qt[u].y, s);
            s = dot4_i8(qc[u].z, qt[u].z, s);
            s = dot4_i8(qc[u].w, qt[u].w, s);
            acc[u] = s;
        }
        #pragma unroll
        for (int u = 0; u < 4; ++u) {
            acc[u] += __shfl_xor(acc[u], 4);
            acc[u] += __shfl_xor(acc[u], 2);
            acc[u] += __shfl_xor(acc[u], 1);
        }
        if (lane == 0) {
            vfloat4 o;
            o.x = (float)acc[0] * sc[0] * st[0];
            o.y = (float)acc[1] * sc[1] * st[1];
            o.z = (float)acc[2] * sc[2] * st[2];
            o.w = (float)acc[3] * sc[3] * st[3];
            __builtin_nontemporal_store(o, reinterpret_cast<vfloat4*>(out + p0));
        }
    } else {
        for (int u = 0; u < 4 && p0 + u < n; ++u) {
            const int pi = p0 + u;
            const int ci = ctx_idx[pi];
            const int ti = tgt_idx[pi];
            const int4 qc = *reinterpret_cast<const int4*>(cxt_q + (size_t)ci * D + lane * 16);
            const int4 qt = *reinterpret_cast<const int4*>(tgt_q + (size_t)ti * D + lane * 16);
            int s = dot4_i8(qc.x, qt.x, 0);
            s = dot4_i8(qc.y, qt.y, s);
            s = dot4_i8(qc.z, qt.z, s);
            s = dot4_i8(qc.w, qt.w, s);
            s += __shfl_xor(s, 4);
            s += __shfl_xor(s, 2);
            s += __shfl_xor(s, 1);
            if (lane == 0) out[pi] = (float)s * cxt_s[ci] * tgt_s[ti];
        }
    }
}

// ---- Fallback (ws too small): fp32 direct ----
__global__ __launch_bounds__(256) void gather_dot_f32_kernel(
    const int* __restrict__ ctx_idx, const int* __restrict__ tgt_idx,
    const float* __restrict__ cxt_w, const float* __restrict__ tgt_w,
    float* __restrict__ out, int n)
{
    const int lane = threadIdx.x & 31;
    const long long g = ((long long)blockIdx.x * blockDim.x + threadIdx.x) >> 5;
    const int pair = (int)g;
    if (pair >= n) return;
    const float4 c = reinterpret_cast<const float4*>(cxt_w + (size_t)ctx_idx[pair] * D)[lane];
    const float4 t = reinterpret_cast<const float4*>(tgt_w + (size_t)tgt_idx[pair] * D)[lane];
    float s = c.x * t.x;
    s = fmaf(c.y, t.y, s);
    s = fmaf(c.z, t.z, s);
    s = fmaf(c.w, t.w, s);
    s += __shfl_xor(s, 16);
    s += __shfl_xor(s, 8);
    s += __shfl_xor(s, 4);
    s += __shfl_xor(s, 2);
    s += __shfl_xor(s, 1);
    if (lane == 0) out[pair] = s;
}

extern "C" void kernel_launch(void* const* d_in, const int* in_sizes, int n_in,
                              void* d_out, int out_size, void* d_ws, size_t ws_size,
                              hipStream_t stream) {
    const int*   ctx_idx = (const int*)d_in[0];
    const int*   tgt_idx = (const int*)d_in[1];
    const float* cxt_w   = (const float*)d_in[2];
    const float* tgt_w   = (const float*)d_in[3];
    float*       out     = (float*)d_out;

    const int n = in_sizes[0];        // N pairs
    const int elems = in_sizes[2];    // V*D per table
    const int V = elems / D;

    const size_t qtab = (size_t)V * D;                    // bytes per int8 table
    const size_t need = 2 * qtab + 2 * (size_t)V * sizeof(float) + 64;

    if (ws_size >= need) {
        char* p = (char*)d_ws;
        signed char* cxt_q = (signed char*)p;  p += qtab;
        signed char* tgt_q = (signed char*)p;  p += qtab;
        float* cxt_s = (float*)p;              p += (size_t)V * sizeof(float);
        float* tgt_s = (float*)p;

        // Pass 1: quantize both tables (16 rows per block).
        const int conv_grid = (2 * V + 15) / 16;
        convert_int8_kernel<<<conv_grid, 256, 0, stream>>>(
            cxt_w, tgt_w, cxt_q, tgt_q, cxt_s, tgt_s, V);

        // Pass 2: gather + int8 dot. 8 lanes/pair, 4 pairs/group -> 128 pairs/block.
        const int pairs_per_block = (256 / 8) * 4;
        const int grid = (n + pairs_per_block - 1) / pairs_per_block;
        gather_dot_q_kernel<<<grid, 256, 0, stream>>>(
            ctx_idx, tgt_idx, cxt_q, tgt_q, cxt_s, tgt_s, out, n);
    } else {
        gather_dot_f32_kernel<<<(n + 7) / 8, 256, 0, stream>>>(
            ctx_idx, tgt_idx, cxt_w, tgt_w, out, n);
    }
}